// Round 6
// baseline (28163.959 us; speedup 1.0000x reference)
//
#include <hip/hip_runtime.h>

// Problem constants (B,T,S,L,D_IN,OUT,W = 256,512,256,36,8,10,256)
#define Tt   512
#define Ll   36
#define DIN  8
#define OUTd 10

typedef __attribute__((ext_vector_type(8))) short short8;
typedef __attribute__((ext_vector_type(4))) float f32x4;

__device__ __forceinline__ unsigned short f2bf(float f) {
    union { float f; unsigned int u; } v; v.f = f;
    unsigned int r = v.u + 0x7fffu + ((v.u >> 16) & 1u);   // RNE
    return (unsigned short)(r >> 16);
}
__device__ __forceinline__ float bf2f(unsigned short u) {
    union { unsigned int u; float f; } v; v.u = ((unsigned int)u) << 16;
    return v.f;
}
__device__ __forceinline__ float sp_f(float x) {      // jax.nn.softplus
    return fmaxf(x, 0.f) + __logf(1.f + __expf(-fabsf(x)));
}
__device__ __forceinline__ float tanh_f(float x) {
    float e = __expf(2.f * x);
    return 1.f - 2.f / (e + 1.f);
}

// ---- agent-scope (sc1 / LLC-coherent) helpers: cross-XCD-safe ----
__device__ __forceinline__ unsigned long long ldg64(const void* p) {
    return __hip_atomic_load((const unsigned long long*)p, __ATOMIC_RELAXED, __HIP_MEMORY_SCOPE_AGENT);
}
__device__ __forceinline__ void stg64(void* p, unsigned long long v) {
    __hip_atomic_store((unsigned long long*)p, v, __ATOMIC_RELAXED, __HIP_MEMORY_SCOPE_AGENT);
}
__device__ __forceinline__ void sth(unsigned short* p, unsigned short v) {
    __hip_atomic_store(p, v, __ATOMIC_RELAXED, __HIP_MEMORY_SCOPE_AGENT);
}
union U64F2 { unsigned long long u; float f[2]; unsigned short s[4]; };

// ---- LDS layout (target <= 80 KB for 2 blocks/CU) ----
struct GScr {
    short hh[16*264], hl[16*264];      // gathered h(t) hi/lo; ml overlays hh..z1l after stage2
    short z1h[16*264], z1l[16*264];    // stage-1 activations
    short z2h[16*264], z2l[16*264];    // stage-2 activations
    float lss[2*576];                  // logsigs slice, double-buffered
};                                      // 55296 B
struct IScr { float x0s[32][DIN]; float h1[32*257]; float h2[32*257]; };  // 66816 B
union  Scr  { GScr g; IScr in; };       // 66816 B (+hloc+rtmp ≈ 66 KB total)

// ---- full-grid tree barrier (phase 0 only); 512 blocks, 8 groups of 64 ----
__device__ __forceinline__ void gbar(int* bar, int gen) {
    __syncthreads();
    if (threadIdx.x == 0) {
        const int g = blockIdx.x & 7;
        int old = __hip_atomic_fetch_add(bar + g * 32, 1, __ATOMIC_RELAXED, __HIP_MEMORY_SCOPE_AGENT);
        if (old == gen * 64 - 1) {
            int o2 = __hip_atomic_fetch_add(bar + 8 * 32, 1, __ATOMIC_RELAXED, __HIP_MEMORY_SCOPE_AGENT);
            if (o2 == gen * 8 - 1) {
#pragma unroll
                for (int gg = 0; gg < 8; ++gg)
                    __hip_atomic_store(bar + (9 + gg) * 32, gen, __ATOMIC_RELAXED, __HIP_MEMORY_SCOPE_AGENT);
            }
        }
        while (__hip_atomic_load(bar + (9 + g) * 32, __ATOMIC_RELAXED, __HIP_MEMORY_SCOPE_AGENT) < gen)
            __builtin_amdgcn_s_sleep(2);
    }
    __syncthreads();
}

// ---- chunk-local barrier: 32 blocks on one monotone counter ----
__device__ __forceinline__ void cbar(int* c, int gen) {
    __syncthreads();   // drains each wave's sc1 stores (vmcnt 0) before arrive
    if (threadIdx.x == 0) {
        __hip_atomic_fetch_add(c, 1, __ATOMIC_RELAXED, __HIP_MEMORY_SCOPE_AGENT);
        while (__hip_atomic_load(c, __ATOMIC_RELAXED, __HIP_MEMORY_SCOPE_AGENT) < gen * 32)
            __builtin_amdgcn_s_sleep(1);
    }
    __syncthreads();
}

// cast 8 consecutive k of W[n][k] (N x 256) into frag-contiguous transposed layout:
// element (n,k) -> ((k>>5)*N + n)*32 + ((k>>3)&3)*8 + (k&7)
__device__ __forceinline__ void cast_w8n(const float* src, unsigned short* dh,
                                         unsigned short* dl, long u, int N) {
    long n = u >> 5; int k8 = (int)(u & 31);
    const float* sp = src + n * 256 + k8 * 8;
    f32x4 f0 = *(const f32x4*)sp;
    f32x4 f1 = *(const f32x4*)(sp + 4);
    U64F2 H0, H1, L0, L1;
#pragma unroll
    for (int q = 0; q < 4; ++q) {
        unsigned short a = f2bf(f0[q]); H0.s[q] = a; L0.s[q] = f2bf(f0[q] - bf2f(a));
        unsigned short b = f2bf(f1[q]); H1.s[q] = b; L1.s[q] = f2bf(f1[q] - bf2f(b));
    }
    long d = ((long)(k8 >> 2) * N + n) * 32 + (k8 & 3) * 8;
    stg64(dh + d, H0.u);  stg64(dh + d + 4, H1.u);
    stg64(dl + d, L0.u);  stg64(dl + d + 4, L1.u);
}

// one MLP stage for 16 rows, 4-wave version: wave owns 4 n-tiles (4*wv+j).
// Z = softplus(A @ B^T + bias); A/Z in LDS [16][264] hi/lo, B global frag-contiguous.
#define MLP_STAGE16(Ah, Al, Bh, Bl, BIAS, Zh, Zl) do {                                      \
    f32x4 acc_[4] = {zero4, zero4, zero4, zero4};                                            \
    for (int k0_ = 0; k0_ < 256; k0_ += 32) {                                                \
      short8 ah_ = *(const short8*)(const void*)&(Ah)[l15 * 264 + k0_ + quad * 8];           \
      short8 al_ = *(const short8*)(const void*)&(Al)[l15 * 264 + k0_ + quad * 8];           \
      _Pragma("unroll")                                                                      \
      for (int j_ = 0; j_ < 4; ++j_) {                                                       \
        int n_ = (4 * wv + j_) * 16 + l15;                                                   \
        long bo_ = ((long)(k0_ >> 5) * 256 + n_) * 32 + quad * 8;                            \
        short8 bh_ = *(const short8*)(const void*)((Bh) + bo_);                              \
        short8 bl_ = *(const short8*)(const void*)((Bl) + bo_);                              \
        acc_[j_] = __builtin_amdgcn_mfma_f32_16x16x32_bf16(ah_, bh_, acc_[j_], 0, 0, 0);     \
        acc_[j_] = __builtin_amdgcn_mfma_f32_16x16x32_bf16(ah_, bl_, acc_[j_], 0, 0, 0);     \
        acc_[j_] = __builtin_amdgcn_mfma_f32_16x16x32_bf16(al_, bh_, acc_[j_], 0, 0, 0);     \
      }                                                                                      \
    }                                                                                        \
    _Pragma("unroll")                                                                        \
    for (int j_ = 0; j_ < 4; ++j_) {                                                         \
      int n_ = (4 * wv + j_) * 16 + l15;                                                     \
      float bs_ = (BIAS)[n_];                                                                \
      _Pragma("unroll")                                                                      \
      for (int r_ = 0; r_ < 4; ++r_) {                                                       \
        int row_ = quad * 4 + r_;                                                            \
        float v_ = sp_f(acc_[j_][r_] + bs_);                                                 \
        unsigned short hi_ = f2bf(v_);                                                       \
        (Zh)[row_ * 264 + n_] = (short)hi_;                                                  \
        (Zl)[row_ * 264 + n_] = (short)f2bf(v_ - bf2f(hi_));                                 \
      }                                                                                      \
    }                                                                                        \
  } while (0)

__global__ __launch_bounds__(256, 2) void rde_fused6(
    const float* __restrict__ x0, const float* __restrict__ logsigs,
    const float* __restrict__ iW1, const float* __restrict__ ib1,
    const float* __restrict__ iW2, const float* __restrict__ ib2,
    const float* __restrict__ iW3, const float* __restrict__ ib3,
    const float* __restrict__ vW1, const float* __restrict__ vb1,
    const float* __restrict__ vW2, const float* __restrict__ vb2,
    const float* __restrict__ vW3, const float* __restrict__ vb3,
    const float* __restrict__ roW, const float* __restrict__ rob,
    float* __restrict__ out,
    unsigned short* hhA, unsigned short* hlA,
    unsigned short* hhB, unsigned short* hlB,
    unsigned short* w1th, unsigned short* w1tl,
    unsigned short* w2th, unsigned short* w2tl,
    unsigned short* w3th, unsigned short* w3tl, int* slots) {
    __shared__ Scr S;
    __shared__ float hloc[128];   // owned h sub-tile [16 rows x 8 s], exact f32
    __shared__ float rtmp[40];    // readout partials (4 waves x 10)
    const int tid = threadIdx.x, blk = blockIdx.x;
    const int lane = tid & 63, wv = tid >> 6, quad = lane >> 4, l15 = lane & 15;
    // blk = (p<<7)|(chunk<<3)|x : chunk=(blk>>3)&15 (16 chunks of 16 batch rows),
    // slot = (x<<2)|p in 0..31 (8 s-cols / 288 W3 rows). Same-XCD blocks (x fixed)
    // share only 4 W3 slices (~1.2 MB) -> L2-resident. Bijective.
    const int chunk = (blk >> 3) & 15;
    const int sl = ((blk & 7) << 2) | ((blk >> 7) & 3);
    const int b0c16 = chunk * 16;        // 16 batch rows owned by this chunk
    const int s0g = sl * 8;              // owned s-slice (8 cols)
    const int n0g = sl * 288;            // owned W3 n-slice
    // chunk counters at slots+1024: disjoint from gbar's range [0, 512]
    int* cb = slots + 1024 + chunk * 32;
    const f32x4 zero4 = {0.f, 0.f, 0.f, 0.f};
    // W3 n-tile assignment: 18 tiles over 4 waves: wave wv owns {wv+4i}, waves 0,1 get 5
    const int nnt = (wv < 2) ? 5 : 4;
    float* ml = (float*)S.g.hh;          // [16][292] f32, overlays hh/hl/z1h/z1l (dead after stage2)

    // ===== phase 0: init MLP (blk<8), W1/W2 cast (8..15), W3 transposed cast (16..511) =====
    if (blk < 8) {
        IScr& I = S.in;
        const int b0 = blk * 32;
        I.x0s[tid >> 3][tid & 7] = x0[(b0 + (tid >> 3)) * DIN + (tid & 7)];
        __syncthreads();
        const int j = tid;
        {
            float w[DIN];
#pragma unroll
            for (int k = 0; k < DIN; ++k) w[k] = iW1[j * DIN + k];
            float bias = ib1[j];
            for (int r = 0; r < 32; ++r) {
                float acc = bias;
#pragma unroll
                for (int k = 0; k < DIN; ++k) acc += I.x0s[r][k] * w[k];
                I.h1[r * 257 + j] = sp_f(acc);
            }
        }
        __syncthreads();
        {
            float bias = ib2[j];
            for (int rb = 0; rb < 4; ++rb) {
                float a8[8];
#pragma unroll
                for (int rr = 0; rr < 8; ++rr) a8[rr] = bias;
                for (int k = 0; k < 256; ++k) {
                    float wvv = iW2[j * 256 + k];
#pragma unroll
                    for (int rr = 0; rr < 8; ++rr) a8[rr] += I.h1[(rb * 8 + rr) * 257 + k] * wvv;
                }
#pragma unroll
                for (int rr = 0; rr < 8; ++rr) I.h2[(rb * 8 + rr) * 257 + j] = sp_f(a8[rr]);
            }
        }
        __syncthreads();
        {
            float bias = ib3[j];
            for (int rb = 0; rb < 4; ++rb) {
                float a8[8];
#pragma unroll
                for (int rr = 0; rr < 8; ++rr) a8[rr] = bias;
                for (int k = 0; k < 256; ++k) {
                    float wvv = iW3[j * 256 + k];
#pragma unroll
                    for (int rr = 0; rr < 8; ++rr) a8[rr] += I.h2[(rb * 8 + rr) * 257 + k] * wvv;
                }
#pragma unroll
                for (int rr = 0; rr < 8; ++rr) {   // publish h0 pre-split
                    float v = a8[rr];
                    unsigned short hi = f2bf(v);
                    sth(&hhA[(b0 + rb * 8 + rr) * 256 + j], hi);
                    sth(&hlA[(b0 + rb * 8 + rr) * 256 + j], f2bf(v - bf2f(hi)));
                }
            }
        }
    } else if (blk < 16) {
        const int idx = blk - 8;
        const float* src = (idx < 4) ? vW1 : vW2;
        unsigned short* dh = (idx < 4) ? w1th : w2th;
        unsigned short* dl = (idx < 4) ? w1tl : w2tl;
        const int part = idx & 3;
        for (int u = part * 2048 + tid; u < (part + 1) * 2048; u += 256)
            cast_w8n(src, dh, dl, u, 256);
    } else {
        for (long u = (long)(blk - 16) * 256 + tid; u < 9216L * 32; u += 496L * 256)
            cast_w8n(vW3, w3th, w3tl, u, 9216);
    }
    gbar(slots, 1);

    // init owned h sub-tile [16 x 8] (hi+lo reconstruction, ~1e-5 rel)
    if (tid < 32) {
        int r = tid >> 1, q = tid & 1;
        U64F2 a, b;
        a.u = ldg64(hhA + (b0c16 + r) * 256 + s0g + q * 4);
        b.u = ldg64(hlA + (b0c16 + r) * 256 + s0g + q * 4);
#pragma unroll
        for (int j = 0; j < 4; ++j) hloc[r * 8 + q * 4 + j] = bf2f(a.s[j]) + bf2f(b.s[j]);
    }
    // prefetch logsigs slice for t=0 into buffer 0
    for (int i = tid; i < 16 * Ll; i += 256) {
        int r = i / Ll, l = i - r * Ll;
        S.g.lss[i] = logsigs[((long)(b0c16 + r) * Tt) * Ll + l];
    }

    // ================= main scan: one chunk-local barrier per step =================
    int lgen = 0;
    for (int t = 0; t < Tt; ++t) {
        GScr& G = S.g;
        const unsigned short* hhs = (t & 1) ? hhB : hhA;
        const unsigned short* hls = (t & 1) ? hlB : hlA;
        unsigned short* hhd = (t & 1) ? hhA : hhB;
        unsigned short* hld = (t & 1) ? hlA : hlB;

        // ---- gather h(t) [16 rows x 256] hi/lo into LDS (coalesced u64 copies) ----
        for (int u = tid; u < 1024; u += 256) {
            int r = u >> 6, c4 = (u & 63) * 4;
            *(unsigned long long*)(void*)&G.hh[r * 264 + c4] = ldg64(hhs + (b0c16 + r) * 256 + c4);
            *(unsigned long long*)(void*)&G.hl[r * 264 + c4] = ldg64(hls + (b0c16 + r) * 256 + c4);
        }
        __syncthreads();

        // ---- readout partials for row b0c16+sl (blocks sl<16 cover all 16 rows) ----
        if (sl < 16 && lane < OUTd) {
            const int o = lane;
            float acc = 0.f;
            const short* ph = &G.hh[sl * 264 + wv * 64];
            const short* pl = &G.hl[sl * 264 + wv * 64];
            const float* wp = roW + o * 256 + wv * 64;
            for (int s = 0; s < 64; s += 8) {
                short8 vh = *(const short8*)(const void*)(ph + s);
                short8 vl = *(const short8*)(const void*)(pl + s);
                f32x4 w0 = *(const f32x4*)(wp + s);
                f32x4 w1 = *(const f32x4*)(wp + s + 4);
#pragma unroll
                for (int q = 0; q < 4; ++q) {
                    acc += (bf2f((unsigned short)vh[q]) + bf2f((unsigned short)vl[q])) * w0[q];
                    acc += (bf2f((unsigned short)vh[q + 4]) + bf2f((unsigned short)vl[q + 4])) * w1[q];
                }
            }
            rtmp[wv * 10 + o] = acc;
        }

        // ---- stage 1: z1 = sp(h W1^T) ----
        MLP_STAGE16(G.hh, G.hl, w1th, w1tl, vb1, G.z1h, G.z1l);
        __syncthreads();

        if (sl < 16 && tid < OUTd)
            out[((long)(b0c16 + sl) * 513 + t) * OUTd + tid] =
                rob[tid] + rtmp[tid] + rtmp[10 + tid] + rtmp[20 + tid] + rtmp[30 + tid];

        // ---- stage 2: z2 = sp(z1 W2^T) ----
        MLP_STAGE16(G.z1h, G.z1l, w2th, w2tl, vb2, G.z2h, G.z2l);
        __syncthreads();

        // ---- W3 GEMM: m-pre = z2 @ W3slice^T (288 n, B direct from global L2) ----
        {
            f32x4 acc[5];
#pragma unroll
            for (int i = 0; i < 5; ++i) acc[i] = zero4;
            for (int kk = 0; kk < 8; ++kk) {
                short8 ah = *(const short8*)(const void*)&G.z2h[l15 * 264 + kk * 32 + quad * 8];
                short8 al = *(const short8*)(const void*)&G.z2l[l15 * 264 + kk * 32 + quad * 8];
#pragma unroll
                for (int i = 0; i < 5; ++i) {
                    if (i < nnt) {
                        int tile = wv + 4 * i;          // i==4 only for wv<2: tiles 16,17
                        long n = (long)n0g + tile * 16 + l15;
                        long bo = ((long)kk * 9216 + n) * 32 + quad * 8;
                        short8 bh = *(const short8*)(const void*)(w3th + bo);
                        short8 bl = *(const short8*)(const void*)(w3tl + bo);
                        acc[i] = __builtin_amdgcn_mfma_f32_16x16x32_bf16(ah, bh, acc[i], 0, 0, 0);
                        acc[i] = __builtin_amdgcn_mfma_f32_16x16x32_bf16(ah, bl, acc[i], 0, 0, 0);
                        acc[i] = __builtin_amdgcn_mfma_f32_16x16x32_bf16(al, bh, acc[i], 0, 0, 0);
                    }
                }
            }
            __syncthreads();   // all reads of hh/z1 region done -> safe to overlay ml
            // tanh epilogue -> ml [16][292] f32 (overlay)
#pragma unroll
            for (int i = 0; i < 5; ++i) {
                if (i < nnt) {
                    int tile = wv + 4 * i;
                    int nloc = tile * 16 + l15;
                    float bias = vb3[n0g + nloc];
#pragma unroll
                    for (int r = 0; r < 4; ++r) {
                        int row = quad * 4 + r;
                        ml[row * 292 + nloc] = tanh_f(acc[i][r] + bias);
                    }
                }
            }
        }
        __syncthreads();

        // ---- l-contraction: thread (r, sL) owns h[r][s0g+sL]: hloc += dot36 ----
        if (tid < 128) {
            int r = tid >> 3, sL = tid & 7;
            const f32x4* mp = (const f32x4*)(const void*)&ml[r * 292 + sL * 36];
            const f32x4* lp = (const f32x4*)(const void*)&G.lss[(t & 1) * 576 + r * 36];
            float a = 0.f;
#pragma unroll
            for (int q = 0; q < 9; ++q) {
                f32x4 m4 = mp[q], l4 = lp[q];
                a += m4[0] * l4[0] + m4[1] * l4[1] + m4[2] * l4[2] + m4[3] * l4[3];
            }
            hloc[tid] += a;
        }
        __syncthreads();

        // ---- publish owned h sub-tile [16 x 8] pre-split to the other buffer ----
        if (tid < 32) {
            int r = tid >> 1, q = tid & 1;
            U64F2 H, L;
#pragma unroll
            for (int j = 0; j < 4; ++j) {
                float v = hloc[r * 8 + q * 4 + j];
                unsigned short hi = f2bf(v);
                H.s[j] = hi;
                L.s[j] = f2bf(v - bf2f(hi));
            }
            stg64(hhd + (b0c16 + r) * 256 + s0g + q * 4, H.u);
            stg64(hld + (b0c16 + r) * 256 + s0g + q * 4, L.u);
        }
        // ---- prefetch logsigs(t+1) into the other lss buffer (h-independent) ----
        if (t + 1 < Tt) {
            for (int i = tid; i < 16 * Ll; i += 256) {
                int r = i / Ll, l = i - r * Ll;
                G.lss[((t + 1) & 1) * 576 + i] =
                    logsigs[((long)(b0c16 + r) * Tt + (t + 1)) * Ll + l];
            }
        }
        cbar(cb, ++lgen);
    }

    // ---- final readout out[:, 512, :]: blocks sl<16, h(512) in A buffers (Tt even) ----
    if (sl < 16) {
        float* fb = ml;   // >= 256 floats
        if (tid < 64) {
            U64F2 a, b;
            a.u = ldg64(hhA + (long)(b0c16 + sl) * 256 + tid * 4);
            b.u = ldg64(hlA + (long)(b0c16 + sl) * 256 + tid * 4);
#pragma unroll
            for (int q = 0; q < 4; ++q) fb[tid * 4 + q] = bf2f(a.s[q]) + bf2f(b.s[q]);
        }
        __syncthreads();
        if (tid < OUTd) {
            float acc = rob[tid];
            const float* wp = roW + tid * 256;
            for (int s = 0; s < 256; s += 4) {
                f32x4 hv = *(const f32x4*)(fb + s);
                f32x4 w4 = *(const f32x4*)(wp + s);
                acc += hv[0] * w4[0] + hv[1] * w4[1] + hv[2] * w4[2] + hv[3] * w4[3];
            }
            out[((long)(b0c16 + sl) * 513 + Tt) * OUTd + tid] = acc;
        }
    }
}

extern "C" void kernel_launch(void* const* d_in, const int* in_sizes, int n_in,
                              void* d_out, int out_size, void* d_ws, size_t ws_size,
                              hipStream_t stream) {
    const float* x0      = (const float*)d_in[0];
    const float* logsigs = (const float*)d_in[1];
    const float* iW1 = (const float*)d_in[2];
    const float* ib1 = (const float*)d_in[3];
    const float* iW2 = (const float*)d_in[4];
    const float* ib2 = (const float*)d_in[5];
    const float* iW3 = (const float*)d_in[6];
    const float* ib3 = (const float*)d_in[7];
    const float* vW1 = (const float*)d_in[8];
    const float* vb1 = (const float*)d_in[9];
    const float* vW2 = (const float*)d_in[10];
    const float* vb2 = (const float*)d_in[11];
    const float* vW3 = (const float*)d_in[12];
    const float* vb3 = (const float*)d_in[13];
    const float* roW = (const float*)d_in[14];
    const float* rob = (const float*)d_in[15];
    float* out = (float*)d_out;

    char* p = (char*)d_ws;
    unsigned short* hhA  = (unsigned short*)p;                // 131072 B
    unsigned short* hlA  = (unsigned short*)(p + 131072);     // 131072 B
    unsigned short* hhB  = (unsigned short*)(p + 262144);     // 131072 B
    unsigned short* hlB  = (unsigned short*)(p + 393216);     // 131072 B
    unsigned short* w1th = (unsigned short*)(p + 524288);     // 131072 B
    unsigned short* w1tl = (unsigned short*)(p + 655360);     // 131072 B
    unsigned short* w2th = (unsigned short*)(p + 786432);     // 131072 B
    unsigned short* w2tl = (unsigned short*)(p + 917504);     // 131072 B
    unsigned short* w3th = (unsigned short*)(p + 1048576);    // 4718592 B
    unsigned short* w3tl = (unsigned short*)(p + 5767168);    // 4718592 B
    int* slots           = (int*)(p + 10485760);              // gbar [0,512], cbar [1024,1536]

    hipMemsetAsync(slots, 0, 8192, stream);
    rde_fused6<<<dim3(512), dim3(256), 0, stream>>>(
        x0, logsigs, iW1, ib1, iW2, ib2, iW3, ib3,
        vW1, vb1, vW2, vb2, vW3, vb3, roW, rob, out,
        hhA, hlA, hhB, hlB, w1th, w1tl, w2th, w2tl, w3th, w3tl, slots);
}

// Round 7
// 15567.062 us; speedup vs baseline: 1.8092x; 1.8092x over previous
//
#include <hip/hip_runtime.h>

// Problem constants (B,T,S,L,D_IN,OUT,W = 256,512,256,36,8,10,256)
#define Tt   512
#define Ll   36
#define DIN  8
#define OUTd 10

typedef __attribute__((ext_vector_type(8))) short short8;
typedef __attribute__((ext_vector_type(4))) float f32x4;

__device__ __forceinline__ unsigned short f2bf(float f) {
    union { float f; unsigned int u; } v; v.f = f;
    unsigned int r = v.u + 0x7fffu + ((v.u >> 16) & 1u);   // RNE
    return (unsigned short)(r >> 16);
}
__device__ __forceinline__ float bf2f(unsigned short u) {
    union { unsigned int u; float f; } v; v.u = ((unsigned int)u) << 16;
    return v.f;
}
__device__ __forceinline__ float sp_f(float x) {      // jax.nn.softplus
    return fmaxf(x, 0.f) + __logf(1.f + __expf(-fabsf(x)));
}
__device__ __forceinline__ float tanh_f(float x) {
    float e = __expf(2.f * x);
    return 1.f - 2.f / (e + 1.f);
}

// ---- agent-scope (sc1 / LLC-coherent) helpers: cross-XCD-safe ----
__device__ __forceinline__ unsigned long long ldg64(const void* p) {
    return __hip_atomic_load((const unsigned long long*)p, __ATOMIC_RELAXED, __HIP_MEMORY_SCOPE_AGENT);
}
__device__ __forceinline__ void stg64(void* p, unsigned long long v) {
    __hip_atomic_store((unsigned long long*)p, v, __ATOMIC_RELAXED, __HIP_MEMORY_SCOPE_AGENT);
}
__device__ __forceinline__ void sth(unsigned short* p, unsigned short v) {
    __hip_atomic_store(p, v, __ATOMIC_RELAXED, __HIP_MEMORY_SCOPE_AGENT);
}
union U64F2 { unsigned long long u; float f[2]; unsigned short s[4]; };

// ---- LDS layout ----
struct GScr {
    short hh[16*264], hl[16*264];      // gathered h(t), hi/lo bf16
    short z1h[16*264], z1l[16*264];    // stage-1 activations
    short z2h[16*264], z2l[16*264];    // stage-2 activations
    float lss[2*576];                  // logsigs slice, double-buffered (prefetch t+1)
    float ml[16*584];                  // tanh(m) slice [16 rows x 576 n]
};                                      // ~92.7 KB
struct IScr { float x0s[32][DIN]; float h1[32*257]; float h2[32*257]; };
union  Scr  { GScr g; IScr in; };

// ---- full-grid tree barrier (phase 0 only); touches slots[0 .. 512] inclusive ----
__device__ __forceinline__ void gbar(int* bar, int gen) {
    __syncthreads();
    if (threadIdx.x == 0) {
        const int g = blockIdx.x & 7;
        int old = __hip_atomic_fetch_add(bar + g * 32, 1, __ATOMIC_RELAXED, __HIP_MEMORY_SCOPE_AGENT);
        if (old == gen * 32 - 1) {
            int o2 = __hip_atomic_fetch_add(bar + 8 * 32, 1, __ATOMIC_RELAXED, __HIP_MEMORY_SCOPE_AGENT);
            if (o2 == gen * 8 - 1) {
#pragma unroll
                for (int gg = 0; gg < 8; ++gg)
                    __hip_atomic_store(bar + (9 + gg) * 32, gen, __ATOMIC_RELAXED, __HIP_MEMORY_SCOPE_AGENT);
            }
        }
        while (__hip_atomic_load(bar + (9 + g) * 32, __ATOMIC_RELAXED, __HIP_MEMORY_SCOPE_AGENT) < gen)
            __builtin_amdgcn_s_sleep(2);
    }
    __syncthreads();
}

// cast 8 consecutive k of W[n][k] (N x 256) into frag-contiguous transposed layout,
// hi/lo pair: element (n,k) -> ((k>>5)*N + n)*32 + ((k>>3)&3)*8 + (k&7)
__device__ __forceinline__ void cast_w8n(const float* src, unsigned short* dh,
                                         unsigned short* dl, long u, int N) {
    long n = u >> 5; int k8 = (int)(u & 31);
    const float* sp = src + n * 256 + k8 * 8;
    f32x4 f0 = *(const f32x4*)sp;
    f32x4 f1 = *(const f32x4*)(sp + 4);
    U64F2 H0, H1, L0, L1;
#pragma unroll
    for (int q = 0; q < 4; ++q) {
        unsigned short a = f2bf(f0[q]); H0.s[q] = a; L0.s[q] = f2bf(f0[q] - bf2f(a));
        unsigned short b = f2bf(f1[q]); H1.s[q] = b; L1.s[q] = f2bf(f1[q] - bf2f(b));
    }
    long d = ((long)(k8 >> 2) * N + n) * 32 + (k8 & 3) * 8;
    stg64(dh + d, H0.u);  stg64(dh + d + 4, H1.u);
    stg64(dl + d, L0.u);  stg64(dl + d + 4, L1.u);
}

// hi-only variant (W3: lo plane dropped — R7)
__device__ __forceinline__ void cast_w8n_hi(const float* src, unsigned short* dh,
                                            long u, int N) {
    long n = u >> 5; int k8 = (int)(u & 31);
    const float* sp = src + n * 256 + k8 * 8;
    f32x4 f0 = *(const f32x4*)sp;
    f32x4 f1 = *(const f32x4*)(sp + 4);
    U64F2 H0, H1;
#pragma unroll
    for (int q = 0; q < 4; ++q) {
        H0.s[q] = f2bf(f0[q]);
        H1.s[q] = f2bf(f1[q]);
    }
    long d = ((long)(k8 >> 2) * N + n) * 32 + (k8 & 3) * 8;
    stg64(dh + d, H0.u);  stg64(dh + d + 4, H1.u);
}

// one MLP stage for 16 rows, 4-wave: wave owns 4 n-tiles (4*wv+j).
// Z = softplus(A @ B^T + bias); A/Z in LDS [16][264] hi/lo, B global frag-contiguous.
#define MLP_STAGE16(Ah, Al, Bh, Bl, BIAS, Zh, Zl) do {                                      \
    f32x4 acc_[4] = {zero4, zero4, zero4, zero4};                                            \
    for (int k0_ = 0; k0_ < 256; k0_ += 32) {                                                \
      short8 ah_ = *(const short8*)(const void*)&(Ah)[l15 * 264 + k0_ + quad * 8];           \
      short8 al_ = *(const short8*)(const void*)&(Al)[l15 * 264 + k0_ + quad * 8];           \
      _Pragma("unroll")                                                                      \
      for (int j_ = 0; j_ < 4; ++j_) {                                                       \
        int n_ = (4 * wv + j_) * 16 + l15;                                                   \
        long bo_ = ((long)(k0_ >> 5) * 256 + n_) * 32 + quad * 8;                            \
        short8 bh_ = *(const short8*)(const void*)((Bh) + bo_);                              \
        short8 bl_ = *(const short8*)(const void*)((Bl) + bo_);                              \
        acc_[j_] = __builtin_amdgcn_mfma_f32_16x16x32_bf16(ah_, bh_, acc_[j_], 0, 0, 0);     \
        acc_[j_] = __builtin_amdgcn_mfma_f32_16x16x32_bf16(ah_, bl_, acc_[j_], 0, 0, 0);     \
        acc_[j_] = __builtin_amdgcn_mfma_f32_16x16x32_bf16(al_, bh_, acc_[j_], 0, 0, 0);     \
      }                                                                                      \
    }                                                                                        \
    _Pragma("unroll")                                                                        \
    for (int j_ = 0; j_ < 4; ++j_) {                                                         \
      int n_ = (4 * wv + j_) * 16 + l15;                                                     \
      float bs_ = (BIAS)[n_];                                                                \
      _Pragma("unroll")                                                                      \
      for (int r_ = 0; r_ < 4; ++r_) {                                                       \
        int row_ = quad * 4 + r_;                                                            \
        float v_ = sp_f(acc_[j_][r_] + bs_);                                                 \
        unsigned short hi_ = f2bf(v_);                                                       \
        (Zh)[row_ * 264 + n_] = (short)hi_;                                                  \
        (Zl)[row_ * 264 + n_] = (short)f2bf(v_ - bf2f(hi_));                                 \
      }                                                                                      \
    }                                                                                        \
  } while (0)

__global__ __launch_bounds__(256, 1) void rde_fused7(
    const float* __restrict__ x0, const float* __restrict__ logsigs,
    const float* __restrict__ iW1, const float* __restrict__ ib1,
    const float* __restrict__ iW2, const float* __restrict__ ib2,
    const float* __restrict__ iW3, const float* __restrict__ ib3,
    const float* __restrict__ vW1, const float* __restrict__ vb1,
    const float* __restrict__ vW2, const float* __restrict__ vb2,
    const float* __restrict__ vW3, const float* __restrict__ vb3,
    const float* __restrict__ roW, const float* __restrict__ rob,
    float* __restrict__ out,
    unsigned short* hhA, unsigned short* hlA,
    unsigned short* hhB, unsigned short* hlB,
    unsigned short* w1th, unsigned short* w1tl,
    unsigned short* w2th, unsigned short* w2tl,
    unsigned short* w3th, unsigned short* w3tl, int* slots) {
    __shared__ Scr S;
    __shared__ float hloc[256];   // owned h sub-tile [16 rows x 16 s], exact f32
    __shared__ float rtmp[44];    // readout partials (4 waves x 10)
    const int tid = threadIdx.x, blk = blockIdx.x;
    const int lane = tid & 63, wv = tid >> 6, quad = lane >> 4, l15 = lane & 15;
    // chunk = (blk>>3)&15, slot = ((blk&7)<<1)|(blk>>7): each XCD's 32 blocks share
    // only 2 W3 slices -> L2-resident (R6 lesson: 1 block/CU + synced chunks is mandatory).
    const int chunk = (blk >> 3) & 15;
    const int sl = ((blk & 7) << 1) | (blk >> 7);
    const int b0c16 = chunk * 16;        // 16 batch rows owned by this chunk
    const int s0g = sl * 16;             // owned s-slice
    const int n0g = sl * 576;            // owned W3 n-slice
    // chunk counters at slots+1024: disjoint from gbar's range [0, 512]
    int* cb = slots + 1024 + chunk * 32;
    const f32x4 zero4 = {0.f, 0.f, 0.f, 0.f};

    // ===== phase 0: init MLP (blk<8), W1/W2 cast (8..15), W3 hi-only cast (16..255) =====
    if (blk < 8) {
        IScr& I = S.in;
        const int b0 = blk * 32;
        I.x0s[tid >> 3][tid & 7] = x0[(b0 + (tid >> 3)) * DIN + (tid & 7)];
        __syncthreads();
        const int j = tid;
        {
            float w[DIN];
#pragma unroll
            for (int k = 0; k < DIN; ++k) w[k] = iW1[j * DIN + k];
            float bias = ib1[j];
            for (int r = 0; r < 32; ++r) {
                float acc = bias;
#pragma unroll
                for (int k = 0; k < DIN; ++k) acc += I.x0s[r][k] * w[k];
                I.h1[r * 257 + j] = sp_f(acc);
            }
        }
        __syncthreads();
        {
            float bias = ib2[j];
            for (int rb = 0; rb < 4; ++rb) {
                float a8[8];
#pragma unroll
                for (int rr = 0; rr < 8; ++rr) a8[rr] = bias;
                for (int k = 0; k < 256; ++k) {
                    float wvv = iW2[j * 256 + k];
#pragma unroll
                    for (int rr = 0; rr < 8; ++rr) a8[rr] += I.h1[(rb * 8 + rr) * 257 + k] * wvv;
                }
#pragma unroll
                for (int rr = 0; rr < 8; ++rr) I.h2[(rb * 8 + rr) * 257 + j] = sp_f(a8[rr]);
            }
        }
        __syncthreads();
        {
            float bias = ib3[j];
            for (int rb = 0; rb < 4; ++rb) {
                float a8[8];
#pragma unroll
                for (int rr = 0; rr < 8; ++rr) a8[rr] = bias;
                for (int k = 0; k < 256; ++k) {
                    float wvv = iW3[j * 256 + k];
#pragma unroll
                    for (int rr = 0; rr < 8; ++rr) a8[rr] += I.h2[(rb * 8 + rr) * 257 + k] * wvv;
                }
#pragma unroll
                for (int rr = 0; rr < 8; ++rr) {   // publish h0 pre-split
                    float v = a8[rr];
                    unsigned short hi = f2bf(v);
                    sth(&hhA[(b0 + rb * 8 + rr) * 256 + j], hi);
                    sth(&hlA[(b0 + rb * 8 + rr) * 256 + j], f2bf(v - bf2f(hi)));
                }
            }
        }
    } else if (blk < 16) {
        const int idx = blk - 8;
        const float* src = (idx < 4) ? vW1 : vW2;
        unsigned short* dh = (idx < 4) ? w1th : w2th;
        unsigned short* dl = (idx < 4) ? w1tl : w2tl;
        const int part = idx & 3;
        for (int u = part * 2048 + tid; u < (part + 1) * 2048; u += 256)
            cast_w8n(src, dh, dl, u, 256);
    } else {
        for (long u = (long)(blk - 16) * 256 + tid; u < 9216L * 32; u += 240L * 256)
            cast_w8n_hi(vW3, w3th, u, 9216);
    }
    gbar(slots, 1);

    // init owned h sub-tile (hi+lo reconstruction, ~1e-5 rel)
    if (tid < 64) {
        int r = tid >> 2, sq = tid & 3;
        U64F2 a, b;
        a.u = ldg64(hhA + (b0c16 + r) * 256 + s0g + sq * 4);
        b.u = ldg64(hlA + (b0c16 + r) * 256 + s0g + sq * 4);
#pragma unroll
        for (int q = 0; q < 4; ++q) hloc[r * 16 + sq * 4 + q] = bf2f(a.s[q]) + bf2f(b.s[q]);
    }
    // prefetch logsigs slice for t=0 into buffer 0
    for (int i = tid; i < 16 * Ll; i += 256) {
        int r = i / Ll, l = i - r * Ll;
        S.g.lss[i] = logsigs[((long)(b0c16 + r) * Tt) * Ll + l];
    }
    __syncthreads();

    // ================= main scan: one chunk-local barrier per step =================
    int lgen = 0;
    for (int t = 0; t < Tt; ++t) {
        GScr& G = S.g;
        const unsigned short* hhs = (t & 1) ? hhB : hhA;
        const unsigned short* hls = (t & 1) ? hlB : hlA;
        unsigned short* hhd = (t & 1) ? hhA : hhB;
        unsigned short* hld = (t & 1) ? hlA : hlB;

        // ---- gather h(t) [16 rows x 256] hi/lo into LDS (coalesced u64 copies) ----
        for (int u = tid; u < 1024; u += 256) {
            int r = u >> 6, c4 = (u & 63) * 4;
            *(unsigned long long*)(void*)&G.hh[r * 264 + c4] = ldg64(hhs + (b0c16 + r) * 256 + c4);
            *(unsigned long long*)(void*)&G.hl[r * 264 + c4] = ldg64(hls + (b0c16 + r) * 256 + c4);
        }
        __syncthreads();

        // ---- readout partials for row b0c16+sl ----
        if (lane < OUTd) {
            const int o = lane;
            float acc = 0.f;
            const short* ph = &G.hh[sl * 264 + wv * 64];
            const short* pl = &G.hl[sl * 264 + wv * 64];
            const float* wp = roW + o * 256 + wv * 64;
            for (int s = 0; s < 64; s += 8) {
                short8 vh = *(const short8*)(const void*)(ph + s);
                short8 vl = *(const short8*)(const void*)(pl + s);
                f32x4 w0 = *(const f32x4*)(wp + s);
                f32x4 w1 = *(const f32x4*)(wp + s + 4);
#pragma unroll
                for (int q = 0; q < 4; ++q) {
                    acc += (bf2f((unsigned short)vh[q]) + bf2f((unsigned short)vl[q])) * w0[q];
                    acc += (bf2f((unsigned short)vh[q + 4]) + bf2f((unsigned short)vl[q + 4])) * w1[q];
                }
            }
            rtmp[wv * 10 + o] = acc;
        }

        // ---- stage 1: z1 = sp(h W1^T) ----
        MLP_STAGE16(G.hh, G.hl, w1th, w1tl, vb1, G.z1h, G.z1l);
        __syncthreads();

        if (tid < OUTd)
            out[((long)(b0c16 + sl) * 513 + t) * OUTd + tid] =
                rob[tid] + rtmp[tid] + rtmp[10 + tid] + rtmp[20 + tid] + rtmp[30 + tid];

        // ---- stage 2: z2 = sp(z1 W2^T) ----
        MLP_STAGE16(G.z1h, G.z1l, w2th, w2tl, vb2, G.z2h, G.z2l);
        __syncthreads();

        // ---- W3 GEMM: m-pre = (z2h+z2l) @ W3hi^T  (hi-only B: halves W3 L2 stream) ----
        {
            f32x4 acc[9];
#pragma unroll
            for (int nt = 0; nt < 9; ++nt) acc[nt] = zero4;
            for (int kk = 0; kk < 8; ++kk) {
                short8 ah = *(const short8*)(const void*)&G.z2h[l15 * 264 + kk * 32 + quad * 8];
                short8 al = *(const short8*)(const void*)&G.z2l[l15 * 264 + kk * 32 + quad * 8];
#pragma unroll
                for (int nt = 0; nt < 9; ++nt) {
                    long n = (long)n0g + wv * 144 + nt * 16 + l15;
                    long bo = ((long)kk * 9216 + n) * 32 + quad * 8;
                    short8 bh = *(const short8*)(const void*)(w3th + bo);
                    acc[nt] = __builtin_amdgcn_mfma_f32_16x16x32_bf16(ah, bh, acc[nt], 0, 0, 0);
                    acc[nt] = __builtin_amdgcn_mfma_f32_16x16x32_bf16(al, bh, acc[nt], 0, 0, 0);
                }
            }
            // tanh epilogue -> ml
#pragma unroll
            for (int nt = 0; nt < 9; ++nt) {
                int nloc = wv * 144 + nt * 16 + l15;
                float bias = vb3[n0g + nloc];
#pragma unroll
                for (int r = 0; r < 4; ++r) {
                    int row = quad * 4 + r;
                    G.ml[row * 584 + nloc] = tanh_f(acc[nt][r] + bias);
                }
            }
        }
        __syncthreads();

        // ---- l-contraction: thread (r, sL) owns h[r][s0g+sL]: hloc += dot36 ----
        {
            int r = tid >> 4, sL = tid & 15;
            const f32x4* mp = (const f32x4*)(const void*)&G.ml[r * 584 + sL * 36];
            const f32x4* lp = (const f32x4*)(const void*)&G.lss[(t & 1) * 576 + r * 36];
            float a = 0.f;
#pragma unroll
            for (int q = 0; q < 9; ++q) {
                f32x4 m4 = mp[q], l4 = lp[q];
                a += m4[0] * l4[0] + m4[1] * l4[1] + m4[2] * l4[2] + m4[3] * l4[3];
            }
            hloc[tid] += a;
        }
        __syncthreads();   // hloc complete (publish below reads all of it)

        // ---- publish owned h sub-tile pre-split (wave 0 only) ----
        if (tid < 64) {
            int r = tid >> 2, sq = tid & 3;
            U64F2 H, L;
#pragma unroll
            for (int q = 0; q < 4; ++q) {
                float v = hloc[r * 16 + sq * 4 + q];
                unsigned short hi = f2bf(v);
                H.s[q] = hi;
                L.s[q] = f2bf(v - bf2f(hi));
            }
            stg64(hhd + (b0c16 + r) * 256 + s0g + sq * 4, H.u);
            stg64(hld + (b0c16 + r) * 256 + s0g + sq * 4, L.u);
        }
        // ---- arrive: RELEASE add (drains wave 0's publish stores first) ----
        ++lgen;
        if (tid == 0)
            __hip_atomic_fetch_add(cb, 1, __ATOMIC_RELEASE, __HIP_MEMORY_SCOPE_AGENT);
        // ---- overlap with barrier wait: prefetch logsigs(t+1) (h-independent) ----
        if (t + 1 < Tt) {
            for (int i = tid; i < 16 * Ll; i += 256) {
                int r = i / Ll, l = i - r * Ll;
                G.lss[((t + 1) & 1) * 576 + i] =
                    logsigs[((long)(b0c16 + r) * Tt + (t + 1)) * Ll + l];
            }
        }
        // ---- per-wave poll (no block-wide sync; gather's own barrier gates reuse).
        // Relaxed is safe: all exchange data moves via sc1/LLC, and publishers'
        // stores reach LLC before their release-add does.
        if (lane == 0) {
            while (__hip_atomic_load(cb, __ATOMIC_RELAXED, __HIP_MEMORY_SCOPE_AGENT) < lgen * 16)
                __builtin_amdgcn_s_sleep(2);
        }
        // wave reconverges here -> proceed to next gather
    }

    // ---- final readout out[:, 512, :]: row b0c16+sl, h(512) in A buffers (Tt even) ----
    {
        __syncthreads();
        float* fb = S.g.ml;   // reuse as f32 row buffer
        if (tid < 64) {
            U64F2 a, b;
            a.u = ldg64(hhA + (long)(b0c16 + sl) * 256 + tid * 4);
            b.u = ldg64(hlA + (long)(b0c16 + sl) * 256 + tid * 4);
#pragma unroll
            for (int q = 0; q < 4; ++q) fb[tid * 4 + q] = bf2f(a.s[q]) + bf2f(b.s[q]);
        }
        __syncthreads();
        if (tid < OUTd) {
            float acc = rob[tid];
            const float* wp = roW + tid * 256;
            for (int s = 0; s < 256; s += 4) {
                f32x4 hv = *(const f32x4*)(fb + s);
                f32x4 w4 = *(const f32x4*)(wp + s);
                acc += hv[0] * w4[0] + hv[1] * w4[1] + hv[2] * w4[2] + hv[3] * w4[3];
            }
            out[((long)(b0c16 + sl) * 513 + Tt) * OUTd + tid] = acc;
        }
    }
}

extern "C" void kernel_launch(void* const* d_in, const int* in_sizes, int n_in,
                              void* d_out, int out_size, void* d_ws, size_t ws_size,
                              hipStream_t stream) {
    const float* x0      = (const float*)d_in[0];
    const float* logsigs = (const float*)d_in[1];
    const float* iW1 = (const float*)d_in[2];
    const float* ib1 = (const float*)d_in[3];
    const float* iW2 = (const float*)d_in[4];
    const float* ib2 = (const float*)d_in[5];
    const float* iW3 = (const float*)d_in[6];
    const float* ib3 = (const float*)d_in[7];
    const float* vW1 = (const float*)d_in[8];
    const float* vb1 = (const float*)d_in[9];
    const float* vW2 = (const float*)d_in[10];
    const float* vb2 = (const float*)d_in[11];
    const float* vW3 = (const float*)d_in[12];
    const float* vb3 = (const float*)d_in[13];
    const float* roW = (const float*)d_in[14];
    const float* rob = (const float*)d_in[15];
    float* out = (float*)d_out;

    char* p = (char*)d_ws;
    unsigned short* hhA  = (unsigned short*)p;                // 131072 B
    unsigned short* hlA  = (unsigned short*)(p + 131072);     // 131072 B
    unsigned short* hhB  = (unsigned short*)(p + 262144);     // 131072 B
    unsigned short* hlB  = (unsigned short*)(p + 393216);     // 131072 B
    unsigned short* w1th = (unsigned short*)(p + 524288);     // 131072 B
    unsigned short* w1tl = (unsigned short*)(p + 655360);     // 131072 B
    unsigned short* w2th = (unsigned short*)(p + 786432);     // 131072 B
    unsigned short* w2tl = (unsigned short*)(p + 917504);     // 131072 B
    unsigned short* w3th = (unsigned short*)(p + 1048576);    // 4718592 B (hi plane)
    unsigned short* w3tl = (unsigned short*)(p + 5767168);    // unused (R7: W3 lo dropped)
    int* slots           = (int*)(p + 10485760);              // gbar [0,512], cbar [1024,1536]

    hipMemsetAsync(slots, 0, 8192, stream);
    rde_fused7<<<dim3(256), dim3(256), 0, stream>>>(
        x0, logsigs, iW1, ib1, iW2, ib2, iW3, ib3,
        vW1, vb1, vW2, vb2, vW3, vb3, roW, rob, out,
        hhA, hlA, hhB, hlB, w1th, w1tl, w2th, w2tl, w3th, w3tl, slots);
}

// Round 8
// 14173.859 us; speedup vs baseline: 1.9870x; 1.0983x over previous
//
#include <hip/hip_runtime.h>

// Problem constants (B,T,S,L,D_IN,OUT,W = 256,512,256,36,8,10,256)
#define Tt   512
#define Ll   36
#define DIN  8
#define OUTd 10

typedef __attribute__((ext_vector_type(8))) _Float16 half8;
typedef __attribute__((ext_vector_type(4))) float f32x4;

__device__ __forceinline__ unsigned short f2h(float f) {
    union { _Float16 h; unsigned short s; } u; u.h = (_Float16)f; return u.s;
}
__device__ __forceinline__ float h2f(unsigned short s) {
    union { unsigned short s; _Float16 h; } u; u.s = s; return (float)u.h;
}
__device__ __forceinline__ float sp_f(float x) {      // jax.nn.softplus
    return fmaxf(x, 0.f) + __logf(1.f + __expf(-fabsf(x)));
}
__device__ __forceinline__ float tanh_f(float x) {
    float e = __expf(2.f * x);
    return 1.f - 2.f / (e + 1.f);
}

// ---- agent-scope (sc1 / LLC-coherent) helpers: cross-XCD-safe ----
__device__ __forceinline__ unsigned long long ldg64(const void* p) {
    return __hip_atomic_load((const unsigned long long*)p, __ATOMIC_RELAXED, __HIP_MEMORY_SCOPE_AGENT);
}
__device__ __forceinline__ void stg64(void* p, unsigned long long v) {
    __hip_atomic_store((unsigned long long*)p, v, __ATOMIC_RELAXED, __HIP_MEMORY_SCOPE_AGENT);
}
__device__ __forceinline__ void sth(unsigned short* p, unsigned short v) {
    __hip_atomic_store(p, v, __ATOMIC_RELAXED, __HIP_MEMORY_SCOPE_AGENT);
}
union U64F2 { unsigned long long u; float f[2]; unsigned short s[4]; };

// ---- LDS layout (all activations single-plane fp16 — R8) ----
struct GScr {
    short hh[16*264];                  // gathered h(t), fp16
    short z1[16*264];                  // stage-1 activations, fp16
    short z2[16*264];                  // stage-2 activations, fp16
    float lss[2*576];                  // logsigs slice, double-buffered
    float ml[16*584];                  // tanh(m) slice [16 rows x 576 n], f32
};                                      // ~67 KB
struct IScr { float x0s[32][DIN]; float h1[32*257]; float h2[32*257]; };
union  Scr  { GScr g; IScr in; };

// ---- full-grid tree barrier (phase 0 only); touches slots[0 .. 512] inclusive ----
__device__ __forceinline__ void gbar(int* bar, int gen) {
    __syncthreads();
    if (threadIdx.x == 0) {
        const int g = blockIdx.x & 7;
        int old = __hip_atomic_fetch_add(bar + g * 32, 1, __ATOMIC_RELAXED, __HIP_MEMORY_SCOPE_AGENT);
        if (old == gen * 32 - 1) {
            int o2 = __hip_atomic_fetch_add(bar + 8 * 32, 1, __ATOMIC_RELAXED, __HIP_MEMORY_SCOPE_AGENT);
            if (o2 == gen * 8 - 1) {
#pragma unroll
                for (int gg = 0; gg < 8; ++gg)
                    __hip_atomic_store(bar + (9 + gg) * 32, gen, __ATOMIC_RELAXED, __HIP_MEMORY_SCOPE_AGENT);
            }
        }
        while (__hip_atomic_load(bar + (9 + g) * 32, __ATOMIC_RELAXED, __HIP_MEMORY_SCOPE_AGENT) < gen)
            __builtin_amdgcn_s_sleep(2);
    }
    __syncthreads();
}

// cast 8 consecutive k of W[n][k] (N x 256) into frag-contiguous transposed fp16:
// element (n,k) -> ((k>>5)*N + n)*32 + ((k>>3)&3)*8 + (k&7)
__device__ __forceinline__ void cast_w8n_h(const float* src, unsigned short* dh,
                                           long u, int N) {
    long n = u >> 5; int k8 = (int)(u & 31);
    const float* sp = src + n * 256 + k8 * 8;
    f32x4 f0 = *(const f32x4*)sp;
    f32x4 f1 = *(const f32x4*)(sp + 4);
    U64F2 H0, H1;
#pragma unroll
    for (int q = 0; q < 4; ++q) {
        H0.s[q] = f2h(f0[q]);
        H1.s[q] = f2h(f1[q]);
    }
    long d = ((long)(k8 >> 2) * N + n) * 32 + (k8 & 3) * 8;
    stg64(dh + d, H0.u);  stg64(dh + d + 4, H1.u);
}

// one MLP stage for 16 rows, 4-wave, fp16: wave owns 4 n-tiles (4*wv+j), 1 MFMA/(k,n).
// Z = softplus(A @ B^T + bias); A/Z in LDS [16][264] fp16, B global frag-contiguous fp16.
#define MLP_STAGE16(Ah, Bh, BIAS, Zh) do {                                                  \
    f32x4 acc_[4] = {zero4, zero4, zero4, zero4};                                            \
    for (int k0_ = 0; k0_ < 256; k0_ += 32) {                                                \
      half8 ah_ = *(const half8*)(const void*)&(Ah)[l15 * 264 + k0_ + quad * 8];             \
      _Pragma("unroll")                                                                      \
      for (int j_ = 0; j_ < 4; ++j_) {                                                       \
        int n_ = (4 * wv + j_) * 16 + l15;                                                   \
        long bo_ = ((long)(k0_ >> 5) * 256 + n_) * 32 + quad * 8;                            \
        half8 bh_ = *(const half8*)(const void*)((Bh) + bo_);                                \
        acc_[j_] = __builtin_amdgcn_mfma_f32_16x16x32_f16(ah_, bh_, acc_[j_], 0, 0, 0);      \
      }                                                                                      \
    }                                                                                        \
    _Pragma("unroll")                                                                        \
    for (int j_ = 0; j_ < 4; ++j_) {                                                         \
      int n_ = (4 * wv + j_) * 16 + l15;                                                     \
      float bs_ = (BIAS)[n_];                                                                \
      _Pragma("unroll")                                                                      \
      for (int r_ = 0; r_ < 4; ++r_) {                                                       \
        int row_ = quad * 4 + r_;                                                            \
        (Zh)[row_ * 264 + n_] = (short)f2h(sp_f(acc_[j_][r_] + bs_));                        \
      }                                                                                      \
    }                                                                                        \
  } while (0)

__global__ __launch_bounds__(256, 1) void rde_fused8(
    const float* __restrict__ x0, const float* __restrict__ logsigs,
    const float* __restrict__ iW1, const float* __restrict__ ib1,
    const float* __restrict__ iW2, const float* __restrict__ ib2,
    const float* __restrict__ iW3, const float* __restrict__ ib3,
    const float* __restrict__ vW1, const float* __restrict__ vb1,
    const float* __restrict__ vW2, const float* __restrict__ vb2,
    const float* __restrict__ vW3, const float* __restrict__ vb3,
    const float* __restrict__ roW, const float* __restrict__ rob,
    float* __restrict__ out,
    unsigned short* hA, unsigned short* hB,
    unsigned short* w1t, unsigned short* w2t, unsigned short* w3t, int* slots) {
    __shared__ Scr S;
    __shared__ float hloc[256];   // owned h sub-tile [16 rows x 16 s], exact f32
    __shared__ float rtmp[44];    // readout partials (4 waves x 10)
    const int tid = threadIdx.x, blk = blockIdx.x;
    const int lane = tid & 63, wv = tid >> 6, quad = lane >> 4, l15 = lane & 15;
    // chunk = (blk>>3)&15, slot = ((blk&7)<<1)|(blk>>7): each XCD's 32 blocks share
    // only 2 W3 slices -> L2-resident (R6 lesson: 1 block/CU + synced chunks mandatory).
    const int chunk = (blk >> 3) & 15;
    const int sl = ((blk & 7) << 1) | (blk >> 7);
    const int b0c16 = chunk * 16;        // 16 batch rows owned by this chunk
    const int s0g = sl * 16;             // owned s-slice
    const int n0g = sl * 576;            // owned W3 n-slice
    int* cb = slots + 1024 + chunk * 32; // disjoint from gbar's [0, 512]
    const f32x4 zero4 = {0.f, 0.f, 0.f, 0.f};

    // ===== phase 0: init MLP (blk<8), W1/W2 fp16 cast (8..15), W3 fp16 cast (16..255) =====
    if (blk < 8) {
        IScr& I = S.in;
        const int b0 = blk * 32;
        I.x0s[tid >> 3][tid & 7] = x0[(b0 + (tid >> 3)) * DIN + (tid & 7)];
        __syncthreads();
        const int j = tid;
        {
            float w[DIN];
#pragma unroll
            for (int k = 0; k < DIN; ++k) w[k] = iW1[j * DIN + k];
            float bias = ib1[j];
            for (int r = 0; r < 32; ++r) {
                float acc = bias;
#pragma unroll
                for (int k = 0; k < DIN; ++k) acc += I.x0s[r][k] * w[k];
                I.h1[r * 257 + j] = sp_f(acc);
            }
        }
        __syncthreads();
        {
            float bias = ib2[j];
            for (int rb = 0; rb < 4; ++rb) {
                float a8[8];
#pragma unroll
                for (int rr = 0; rr < 8; ++rr) a8[rr] = bias;
                for (int k = 0; k < 256; ++k) {
                    float wvv = iW2[j * 256 + k];
#pragma unroll
                    for (int rr = 0; rr < 8; ++rr) a8[rr] += I.h1[(rb * 8 + rr) * 257 + k] * wvv;
                }
#pragma unroll
                for (int rr = 0; rr < 8; ++rr) I.h2[(rb * 8 + rr) * 257 + j] = sp_f(a8[rr]);
            }
        }
        __syncthreads();
        {
            float bias = ib3[j];
            for (int rb = 0; rb < 4; ++rb) {
                float a8[8];
#pragma unroll
                for (int rr = 0; rr < 8; ++rr) a8[rr] = bias;
                for (int k = 0; k < 256; ++k) {
                    float wvv = iW3[j * 256 + k];
#pragma unroll
                    for (int rr = 0; rr < 8; ++rr) a8[rr] += I.h2[(rb * 8 + rr) * 257 + k] * wvv;
                }
#pragma unroll
                for (int rr = 0; rr < 8; ++rr)   // publish h0 as fp16
                    sth(&hA[(b0 + rb * 8 + rr) * 256 + j], f2h(a8[rr]));
            }
        }
    } else if (blk < 16) {
        const int idx = blk - 8;
        const float* src = (idx < 4) ? vW1 : vW2;
        unsigned short* dh = (idx < 4) ? w1t : w2t;
        const int part = idx & 3;
        for (int u = part * 2048 + tid; u < (part + 1) * 2048; u += 256)
            cast_w8n_h(src, dh, u, 256);
    } else {
        for (long u = (long)(blk - 16) * 256 + tid; u < 9216L * 32; u += 240L * 256)
            cast_w8n_h(vW3, w3t, u, 9216);
    }
    gbar(slots, 1);

    // init owned h sub-tile (fp16 -> f32; owned trajectory accumulates in exact f32)
    if (tid < 64) {
        int r = tid >> 2, sq = tid & 3;
        U64F2 a;
        a.u = ldg64(hA + (b0c16 + r) * 256 + s0g + sq * 4);
#pragma unroll
        for (int q = 0; q < 4; ++q) hloc[r * 16 + sq * 4 + q] = h2f(a.s[q]);
    }
    // prefetch logsigs slice for t=0 into buffer 0
    for (int i = tid; i < 16 * Ll; i += 256) {
        int r = i / Ll, l = i - r * Ll;
        S.g.lss[i] = logsigs[((long)(b0c16 + r) * Tt) * Ll + l];
    }
    __syncthreads();

    // ================= main scan: one chunk-local barrier per step =================
    int lgen = 0;
    for (int t = 0; t < Tt; ++t) {
        GScr& G = S.g;
        const unsigned short* hs = (t & 1) ? hB : hA;
        unsigned short* hd = (t & 1) ? hA : hB;

        // ---- gather h(t) [16 rows x 256] fp16 into LDS (coalesced u64 copies) ----
        for (int u = tid; u < 1024; u += 256) {
            int r = u >> 6, c4 = (u & 63) * 4;
            *(unsigned long long*)(void*)&G.hh[r * 264 + c4] = ldg64(hs + (b0c16 + r) * 256 + c4);
        }
        __syncthreads();

        // ---- readout partials for row b0c16+sl ----
        if (lane < OUTd) {
            const int o = lane;
            float acc = 0.f;
            const short* ph = &G.hh[sl * 264 + wv * 64];
            const float* wp = roW + o * 256 + wv * 64;
            for (int s = 0; s < 64; s += 8) {
                half8 vh = *(const half8*)(const void*)(ph + s);
                f32x4 w0 = *(const f32x4*)(wp + s);
                f32x4 w1 = *(const f32x4*)(wp + s + 4);
#pragma unroll
                for (int q = 0; q < 4; ++q) {
                    acc += (float)vh[q] * w0[q];
                    acc += (float)vh[q + 4] * w1[q];
                }
            }
            rtmp[wv * 10 + o] = acc;
        }

        // ---- stage 1: z1 = sp(h W1^T) ----
        MLP_STAGE16(G.hh, w1t, vb1, G.z1);
        __syncthreads();

        if (tid < OUTd)
            out[((long)(b0c16 + sl) * 513 + t) * OUTd + tid] =
                rob[tid] + rtmp[tid] + rtmp[10 + tid] + rtmp[20 + tid] + rtmp[30 + tid];

        // ---- stage 2: z2 = sp(z1 W2^T) ----
        MLP_STAGE16(G.z1, w2t, vb2, G.z2);
        __syncthreads();

        // ---- W3 GEMM: m-pre = z2 @ W3slice^T (fp16 x fp16, 1 MFMA per (k,n)) ----
        {
            f32x4 acc[9];
#pragma unroll
            for (int nt = 0; nt < 9; ++nt) acc[nt] = zero4;
            for (int kk = 0; kk < 8; ++kk) {
                half8 ah = *(const half8*)(const void*)&G.z2[l15 * 264 + kk * 32 + quad * 8];
#pragma unroll
                for (int nt = 0; nt < 9; ++nt) {
                    long n = (long)n0g + wv * 144 + nt * 16 + l15;
                    long bo = ((long)kk * 9216 + n) * 32 + quad * 8;
                    half8 bh = *(const half8*)(const void*)(w3t + bo);
                    acc[nt] = __builtin_amdgcn_mfma_f32_16x16x32_f16(ah, bh, acc[nt], 0, 0, 0);
                }
            }
            // tanh epilogue -> ml
#pragma unroll
            for (int nt = 0; nt < 9; ++nt) {
                int nloc = wv * 144 + nt * 16 + l15;
                float bias = vb3[n0g + nloc];
#pragma unroll
                for (int r = 0; r < 4; ++r) {
                    int row = quad * 4 + r;
                    G.ml[row * 584 + nloc] = tanh_f(acc[nt][r] + bias);
                }
            }
        }
        __syncthreads();

        // ---- l-contraction: thread (r, sL) owns h[r][s0g+sL]: hloc += dot36 ----
        {
            int r = tid >> 4, sL = tid & 15;
            const f32x4* mp = (const f32x4*)(const void*)&G.ml[r * 584 + sL * 36];
            const f32x4* lp = (const f32x4*)(const void*)&G.lss[(t & 1) * 576 + r * 36];
            float a = 0.f;
#pragma unroll
            for (int q = 0; q < 9; ++q) {
                f32x4 m4 = mp[q], l4 = lp[q];
                a += m4[0] * l4[0] + m4[1] * l4[1] + m4[2] * l4[2] + m4[3] * l4[3];
            }
            hloc[tid] += a;
        }
        __syncthreads();   // hloc complete (publish below reads all of it)

        // ---- publish owned h sub-tile fp16 (wave 0 only) ----
        if (tid < 64) {
            int r = tid >> 2, sq = tid & 3;
            U64F2 H;
#pragma unroll
            for (int q = 0; q < 4; ++q) H.s[q] = f2h(hloc[r * 16 + sq * 4 + q]);
            stg64(hd + (b0c16 + r) * 256 + s0g + sq * 4, H.u);
        }
        // ---- arrive: RELEASE add (drains wave 0's publish stores first) ----
        ++lgen;
        if (tid == 0)
            __hip_atomic_fetch_add(cb, 1, __ATOMIC_RELEASE, __HIP_MEMORY_SCOPE_AGENT);
        // ---- overlap with barrier wait: prefetch logsigs(t+1) (h-independent) ----
        if (t + 1 < Tt) {
            for (int i = tid; i < 16 * Ll; i += 256) {
                int r = i / Ll, l = i - r * Ll;
                G.lss[((t + 1) & 1) * 576 + i] =
                    logsigs[((long)(b0c16 + r) * Tt + (t + 1)) * Ll + l];
            }
        }
        // ---- per-wave poll (relaxed safe: publishers' sc1 stores precede release-add) ----
        if (lane == 0) {
            while (__hip_atomic_load(cb, __ATOMIC_RELAXED, __HIP_MEMORY_SCOPE_AGENT) < lgen * 16)
                __builtin_amdgcn_s_sleep(2);
        }
    }

    // ---- final readout out[:, 512, :]: row b0c16+sl, h(512) in hA (Tt even) ----
    {
        __syncthreads();
        float* fb = S.g.ml;   // reuse as f32 row buffer
        if (tid < 64) {
            U64F2 a;
            a.u = ldg64(hA + (long)(b0c16 + sl) * 256 + tid * 4);
#pragma unroll
            for (int q = 0; q < 4; ++q) fb[tid * 4 + q] = h2f(a.s[q]);
        }
        __syncthreads();
        if (tid < OUTd) {
            float acc = rob[tid];
            const float* wp = roW + tid * 256;
            for (int s = 0; s < 256; s += 4) {
                f32x4 hv = *(const f32x4*)(fb + s);
                f32x4 w4 = *(const f32x4*)(wp + s);
                acc += hv[0] * w4[0] + hv[1] * w4[1] + hv[2] * w4[2] + hv[3] * w4[3];
            }
            out[((long)(b0c16 + sl) * 513 + Tt) * OUTd + tid] = acc;
        }
    }
}

extern "C" void kernel_launch(void* const* d_in, const int* in_sizes, int n_in,
                              void* d_out, int out_size, void* d_ws, size_t ws_size,
                              hipStream_t stream) {
    const float* x0      = (const float*)d_in[0];
    const float* logsigs = (const float*)d_in[1];
    const float* iW1 = (const float*)d_in[2];
    const float* ib1 = (const float*)d_in[3];
    const float* iW2 = (const float*)d_in[4];
    const float* ib2 = (const float*)d_in[5];
    const float* iW3 = (const float*)d_in[6];
    const float* ib3 = (const float*)d_in[7];
    const float* vW1 = (const float*)d_in[8];
    const float* vb1 = (const float*)d_in[9];
    const float* vW2 = (const float*)d_in[10];
    const float* vb2 = (const float*)d_in[11];
    const float* vW3 = (const float*)d_in[12];
    const float* vb3 = (const float*)d_in[13];
    const float* roW = (const float*)d_in[14];
    const float* rob = (const float*)d_in[15];
    float* out = (float*)d_out;

    char* p = (char*)d_ws;
    unsigned short* hA   = (unsigned short*)p;                // 131072 B (fp16)
    unsigned short* hB   = (unsigned short*)(p + 131072);     // 131072 B (fp16)
    unsigned short* w1t  = (unsigned short*)(p + 262144);     // 131072 B (fp16)
    unsigned short* w2t  = (unsigned short*)(p + 393216);     // 131072 B (fp16)
    unsigned short* w3t  = (unsigned short*)(p + 524288);     // 4718592 B (fp16)
    int* slots           = (int*)(p + 10485760);              // gbar [0,512], cbar [1024,1536]

    hipMemsetAsync(slots, 0, 8192, stream);
    rde_fused8<<<dim3(256), dim3(256), 0, stream>>>(
        x0, logsigs, iW1, ib1, iW2, ib2, iW3, ib3,
        vW1, vb1, vW2, vb2, vW3, vb3, roW, rob, out,
        hA, hB, w1t, w2t, w3t, slots);
}

// Round 9
// 10015.986 us; speedup vs baseline: 2.8119x; 1.4151x over previous
//
#include <hip/hip_runtime.h>

// Problem constants (B,T,S,L,D_IN,OUT,W = 256,512,256,36,8,10,256)
#define Tt   512
#define Ll   36
#define DIN  8
#define OUTd 10

typedef __attribute__((ext_vector_type(8))) _Float16 half8;
typedef __attribute__((ext_vector_type(4))) float f32x4;

__device__ __forceinline__ unsigned short f2h(float f) {
    union { _Float16 h; unsigned short s; } u; u.h = (_Float16)f; return u.s;
}
__device__ __forceinline__ float h2f(unsigned short s) {
    union { unsigned short s; _Float16 h; } u; u.s = s; return (float)u.h;
}
__device__ __forceinline__ float sp_f(float x) {      // jax.nn.softplus
    return fmaxf(x, 0.f) + __logf(1.f + __expf(-fabsf(x)));
}
__device__ __forceinline__ float tanh_f(float x) {
    float e = __expf(2.f * x);
    return 1.f - 2.f / (e + 1.f);
}

// ---- agent-scope (sc1 / LLC-coherent) helpers: cross-XCD-safe ----
__device__ __forceinline__ unsigned long long ldg64(const void* p) {
    return __hip_atomic_load((const unsigned long long*)p, __ATOMIC_RELAXED, __HIP_MEMORY_SCOPE_AGENT);
}
__device__ __forceinline__ void stg64(void* p, unsigned long long v) {
    __hip_atomic_store((unsigned long long*)p, v, __ATOMIC_RELAXED, __HIP_MEMORY_SCOPE_AGENT);
}
__device__ __forceinline__ void sth(unsigned short* p, unsigned short v) {
    __hip_atomic_store(p, v, __ATOMIC_RELAXED, __HIP_MEMORY_SCOPE_AGENT);
}
union U64F2 { unsigned long long u; float f[2]; unsigned short s[4]; };

// ---- LDS layout (all activations single-plane fp16) ----
struct GScr {
    short hh[16*264];                  // gathered h(t), fp16
    short z1[16*264];                  // stage-1 activations, fp16
    short z2[16*264];                  // stage-2 activations, fp16
    float lss[2*576];                  // logsigs slice, double-buffered
    float ml[16*584];                  // tanh(m) slice [16 rows x 576 n], f32
};                                      // ~67 KB
struct IScr { float x0s[32][DIN]; float h1[32*257]; float h2[32*257]; };
union  Scr  { GScr g; IScr in; };

// ---- full-grid tree barrier (phase 0 only); touches slots[0 .. 512] inclusive ----
__device__ __forceinline__ void gbar(int* bar, int gen) {
    __syncthreads();
    if (threadIdx.x == 0) {
        const int g = blockIdx.x & 7;
        int old = __hip_atomic_fetch_add(bar + g * 32, 1, __ATOMIC_RELAXED, __HIP_MEMORY_SCOPE_AGENT);
        if (old == gen * 32 - 1) {
            int o2 = __hip_atomic_fetch_add(bar + 8 * 32, 1, __ATOMIC_RELAXED, __HIP_MEMORY_SCOPE_AGENT);
            if (o2 == gen * 8 - 1) {
#pragma unroll
                for (int gg = 0; gg < 8; ++gg)
                    __hip_atomic_store(bar + (9 + gg) * 32, gen, __ATOMIC_RELAXED, __HIP_MEMORY_SCOPE_AGENT);
            }
        }
        while (__hip_atomic_load(bar + (9 + g) * 32, __ATOMIC_RELAXED, __HIP_MEMORY_SCOPE_AGENT) < gen)
            __builtin_amdgcn_s_sleep(2);
    }
    __syncthreads();
}

// cast 8 consecutive k of W[n][k] (N x 256) into frag-contiguous transposed fp16:
// element (n,k) -> ((k>>5)*N + n)*32 + ((k>>3)&3)*8 + (k&7)
__device__ __forceinline__ void cast_w8n_h(const float* src, unsigned short* dh,
                                           long u, int N) {
    long n = u >> 5; int k8 = (int)(u & 31);
    const float* sp = src + n * 256 + k8 * 8;
    f32x4 f0 = *(const f32x4*)sp;
    f32x4 f1 = *(const f32x4*)(sp + 4);
    U64F2 H0, H1;
#pragma unroll
    for (int q = 0; q < 4; ++q) {
        H0.s[q] = f2h(f0[q]);
        H1.s[q] = f2h(f1[q]);
    }
    long d = ((long)(k8 >> 2) * N + n) * 32 + (k8 & 3) * 8;
    stg64(dh + d, H0.u);  stg64(dh + d + 4, H1.u);
}

// one MLP stage for 16 rows, 4-wave, fp16, REGISTER-RESIDENT B (R9):
// wave owns 4 n-tiles; WF[j][kt] holds the B-fragment for n-tile j, k-step kt.
// All indices static (fully unrolled) so WF stays in VGPRs.
#define MLP_STAGE16R(Ah, WF, BIAS, Zh) do {                                                 \
    f32x4 acc_[4] = {zero4, zero4, zero4, zero4};                                            \
    _Pragma("unroll")                                                                        \
    for (int kt_ = 0; kt_ < 8; ++kt_) {                                                      \
      half8 ah_ = *(const half8*)(const void*)&(Ah)[l15 * 264 + kt_ * 32 + quad * 8];        \
      _Pragma("unroll")                                                                      \
      for (int j_ = 0; j_ < 4; ++j_)                                                         \
        acc_[j_] = __builtin_amdgcn_mfma_f32_16x16x32_f16(ah_, (WF)[j_][kt_], acc_[j_], 0, 0, 0); \
    }                                                                                        \
    _Pragma("unroll")                                                                        \
    for (int j_ = 0; j_ < 4; ++j_) {                                                         \
      int n_ = (4 * wv + j_) * 16 + l15;                                                     \
      float bs_ = (BIAS)[n_];                                                                \
      _Pragma("unroll")                                                                      \
      for (int r_ = 0; r_ < 4; ++r_) {                                                       \
        int row_ = quad * 4 + r_;                                                            \
        (Zh)[row_ * 264 + n_] = (short)f2h(sp_f(acc_[j_][r_] + bs_));                        \
      }                                                                                      \
    }                                                                                        \
  } while (0)

__global__ __launch_bounds__(256, 1) void rde_fused9(
    const float* __restrict__ x0, const float* __restrict__ logsigs,
    const float* __restrict__ iW1, const float* __restrict__ ib1,
    const float* __restrict__ iW2, const float* __restrict__ ib2,
    const float* __restrict__ iW3, const float* __restrict__ ib3,
    const float* __restrict__ vW1, const float* __restrict__ vb1,
    const float* __restrict__ vW2, const float* __restrict__ vb2,
    const float* __restrict__ vW3, const float* __restrict__ vb3,
    const float* __restrict__ roW, const float* __restrict__ rob,
    float* __restrict__ out,
    unsigned short* hA, unsigned short* hB,
    unsigned short* w1t, unsigned short* w2t, unsigned short* w3t, int* slots) {
    __shared__ Scr S;
    __shared__ float hloc[256];   // owned h sub-tile [16 rows x 16 s], exact f32
    __shared__ float rtmp[44];    // readout partials (4 waves x 10)
    const int tid = threadIdx.x, blk = blockIdx.x;
    const int lane = tid & 63, wv = tid >> 6, quad = lane >> 4, l15 = lane & 15;
    // chunk = (blk>>3)&15, slot = ((blk&7)<<1)|(blk>>7): each XCD's 32 blocks share
    // only 2 W3 slices -> L2-resident (R6 lesson: 1 block/CU + synced chunks mandatory).
    const int chunk = (blk >> 3) & 15;
    const int sl = ((blk & 7) << 1) | (blk >> 7);
    const int b0c16 = chunk * 16;        // 16 batch rows owned by this chunk
    const int s0g = sl * 16;             // owned s-slice
    const int n0g = sl * 576;            // owned W3 n-slice
    int* cb = slots + 1024 + chunk * 32; // disjoint from gbar's [0, 512]
    const f32x4 zero4 = {0.f, 0.f, 0.f, 0.f};

    // ===== phase 0: init MLP (blk<8), W1/W2 fp16 cast (8..15), W3 fp16 cast (16..255) =====
    if (blk < 8) {
        IScr& I = S.in;
        const int b0 = blk * 32;
        I.x0s[tid >> 3][tid & 7] = x0[(b0 + (tid >> 3)) * DIN + (tid & 7)];
        __syncthreads();
        const int j = tid;
        {
            float w[DIN];
#pragma unroll
            for (int k = 0; k < DIN; ++k) w[k] = iW1[j * DIN + k];
            float bias = ib1[j];
            for (int r = 0; r < 32; ++r) {
                float acc = bias;
#pragma unroll
                for (int k = 0; k < DIN; ++k) acc += I.x0s[r][k] * w[k];
                I.h1[r * 257 + j] = sp_f(acc);
            }
        }
        __syncthreads();
        {
            float bias = ib2[j];
            for (int rb = 0; rb < 4; ++rb) {
                float a8[8];
#pragma unroll
                for (int rr = 0; rr < 8; ++rr) a8[rr] = bias;
                for (int k = 0; k < 256; ++k) {
                    float wvv = iW2[j * 256 + k];
#pragma unroll
                    for (int rr = 0; rr < 8; ++rr) a8[rr] += I.h1[(rb * 8 + rr) * 257 + k] * wvv;
                }
#pragma unroll
                for (int rr = 0; rr < 8; ++rr) I.h2[(rb * 8 + rr) * 257 + j] = sp_f(a8[rr]);
            }
        }
        __syncthreads();
        {
            float bias = ib3[j];
            for (int rb = 0; rb < 4; ++rb) {
                float a8[8];
#pragma unroll
                for (int rr = 0; rr < 8; ++rr) a8[rr] = bias;
                for (int k = 0; k < 256; ++k) {
                    float wvv = iW3[j * 256 + k];
#pragma unroll
                    for (int rr = 0; rr < 8; ++rr) a8[rr] += I.h2[(rb * 8 + rr) * 257 + k] * wvv;
                }
#pragma unroll
                for (int rr = 0; rr < 8; ++rr)   // publish h0 as fp16
                    sth(&hA[(b0 + rb * 8 + rr) * 256 + j], f2h(a8[rr]));
            }
        }
    } else if (blk < 16) {
        const int idx = blk - 8;
        const float* src = (idx < 4) ? vW1 : vW2;
        unsigned short* dh = (idx < 4) ? w1t : w2t;
        const int part = idx & 3;
        for (int u = part * 2048 + tid; u < (part + 1) * 2048; u += 256)
            cast_w8n_h(src, dh, u, 256);
    } else {
        for (long u = (long)(blk - 16) * 256 + tid; u < 9216L * 32; u += 240L * 256)
            cast_w8n_h(vW3, w3t, u, 9216);
    }
    gbar(slots, 1);

    // ===== R9: load this wave's W1/W2 B-fragments into registers (t-invariant) =====
    half8 w1f[4][8], w2f[4][8];
#pragma unroll
    for (int j = 0; j < 4; ++j) {
        int n_ = (4 * wv + j) * 16 + l15;
#pragma unroll
        for (int kt = 0; kt < 8; ++kt) {
            long bo = ((long)kt * 256 + n_) * 32 + quad * 8;
            w1f[j][kt] = *(const half8*)(const void*)(w1t + bo);
            w2f[j][kt] = *(const half8*)(const void*)(w2t + bo);
        }
    }

    // init owned h sub-tile (fp16 -> f32; owned trajectory accumulates in exact f32)
    if (tid < 64) {
        int r = tid >> 2, sq = tid & 3;
        U64F2 a;
        a.u = ldg64(hA + (b0c16 + r) * 256 + s0g + sq * 4);
#pragma unroll
        for (int q = 0; q < 4; ++q) hloc[r * 16 + sq * 4 + q] = h2f(a.s[q]);
    }
    // prefetch logsigs slice for t=0 into buffer 0
    for (int i = tid; i < 16 * Ll; i += 256) {
        int r = i / Ll, l = i - r * Ll;
        S.g.lss[i] = logsigs[((long)(b0c16 + r) * Tt) * Ll + l];
    }
    __syncthreads();

    // ================= main scan: one chunk-local barrier per step =================
    int lgen = 0;
    for (int t = 0; t < Tt; ++t) {
        GScr& G = S.g;
        const unsigned short* hs = (t & 1) ? hB : hA;
        unsigned short* hd = (t & 1) ? hA : hB;

        // ---- gather h(t) [16 rows x 256] fp16 into LDS (coalesced u64 copies) ----
        for (int u = tid; u < 1024; u += 256) {
            int r = u >> 6, c4 = (u & 63) * 4;
            *(unsigned long long*)(void*)&G.hh[r * 264 + c4] = ldg64(hs + (b0c16 + r) * 256 + c4);
        }
        __syncthreads();

        // ---- readout partials for row b0c16+sl ----
        if (lane < OUTd) {
            const int o = lane;
            float acc = 0.f;
            const short* ph = &G.hh[sl * 264 + wv * 64];
            const float* wp = roW + o * 256 + wv * 64;
            for (int s = 0; s < 64; s += 8) {
                half8 vh = *(const half8*)(const void*)(ph + s);
                f32x4 w0 = *(const f32x4*)(wp + s);
                f32x4 w1 = *(const f32x4*)(wp + s + 4);
#pragma unroll
                for (int q = 0; q < 4; ++q) {
                    acc += (float)vh[q] * w0[q];
                    acc += (float)vh[q + 4] * w1[q];
                }
            }
            rtmp[wv * 10 + o] = acc;
        }

        // ---- stage 1: z1 = sp(h W1^T)  (B register-resident) ----
        MLP_STAGE16R(G.hh, w1f, vb1, G.z1);
        __syncthreads();

        if (tid < OUTd)
            out[((long)(b0c16 + sl) * 513 + t) * OUTd + tid] =
                rob[tid] + rtmp[tid] + rtmp[10 + tid] + rtmp[20 + tid] + rtmp[30 + tid];

        // ---- stage 2: z2 = sp(z1 W2^T)  (B register-resident) ----
        MLP_STAGE16R(G.z1, w2f, vb2, G.z2);
        __syncthreads();

        // ---- W3 GEMM: m-pre = z2 @ W3slice^T (fp16, streamed from L2) ----
        {
            f32x4 acc[9];
#pragma unroll
            for (int nt = 0; nt < 9; ++nt) acc[nt] = zero4;
            for (int kk = 0; kk < 8; ++kk) {
                half8 ah = *(const half8*)(const void*)&G.z2[l15 * 264 + kk * 32 + quad * 8];
#pragma unroll
                for (int nt = 0; nt < 9; ++nt) {
                    long n = (long)n0g + wv * 144 + nt * 16 + l15;
                    long bo = ((long)kk * 9216 + n) * 32 + quad * 8;
                    half8 bh = *(const half8*)(const void*)(w3t + bo);
                    acc[nt] = __builtin_amdgcn_mfma_f32_16x16x32_f16(ah, bh, acc[nt], 0, 0, 0);
                }
            }
            // tanh epilogue -> ml
#pragma unroll
            for (int nt = 0; nt < 9; ++nt) {
                int nloc = wv * 144 + nt * 16 + l15;
                float bias = vb3[n0g + nloc];
#pragma unroll
                for (int r = 0; r < 4; ++r) {
                    int row = quad * 4 + r;
                    G.ml[row * 584 + nloc] = tanh_f(acc[nt][r] + bias);
                }
            }
        }
        __syncthreads();

        // ---- l-contraction: thread (r, sL) owns h[r][s0g+sL]: hloc += dot36 ----
        {
            int r = tid >> 4, sL = tid & 15;
            const f32x4* mp = (const f32x4*)(const void*)&G.ml[r * 584 + sL * 36];
            const f32x4* lp = (const f32x4*)(const void*)&G.lss[(t & 1) * 576 + r * 36];
            float a = 0.f;
#pragma unroll
            for (int q = 0; q < 9; ++q) {
                f32x4 m4 = mp[q], l4 = lp[q];
                a += m4[0] * l4[0] + m4[1] * l4[1] + m4[2] * l4[2] + m4[3] * l4[3];
            }
            hloc[tid] += a;
        }
        __syncthreads();   // hloc complete (publish below reads all of it)

        // ---- publish owned h sub-tile fp16 (wave 0 only) ----
        if (tid < 64) {
            int r = tid >> 2, sq = tid & 3;
            U64F2 H;
#pragma unroll
            for (int q = 0; q < 4; ++q) H.s[q] = f2h(hloc[r * 16 + sq * 4 + q]);
            stg64(hd + (b0c16 + r) * 256 + s0g + sq * 4, H.u);
        }
        // ---- arrive: RELEASE add (drains wave 0's publish stores first) ----
        ++lgen;
        if (tid == 0)
            __hip_atomic_fetch_add(cb, 1, __ATOMIC_RELEASE, __HIP_MEMORY_SCOPE_AGENT);
        // ---- overlap with barrier wait: prefetch logsigs(t+1) (h-independent) ----
        if (t + 1 < Tt) {
            for (int i = tid; i < 16 * Ll; i += 256) {
                int r = i / Ll, l = i - r * Ll;
                G.lss[((t + 1) & 1) * 576 + i] =
                    logsigs[((long)(b0c16 + r) * Tt + (t + 1)) * Ll + l];
            }
        }
        // ---- per-wave poll (relaxed safe: publishers' sc1 stores precede release-add) ----
        if (lane == 0) {
            while (__hip_atomic_load(cb, __ATOMIC_RELAXED, __HIP_MEMORY_SCOPE_AGENT) < lgen * 16)
                __builtin_amdgcn_s_sleep(2);
        }
    }

    // ---- final readout out[:, 512, :]: row b0c16+sl, h(512) in hA (Tt even) ----
    {
        __syncthreads();
        float* fb = S.g.ml;   // reuse as f32 row buffer
        if (tid < 64) {
            U64F2 a;
            a.u = ldg64(hA + (long)(b0c16 + sl) * 256 + tid * 4);
#pragma unroll
            for (int q = 0; q < 4; ++q) fb[tid * 4 + q] = h2f(a.s[q]);
        }
        __syncthreads();
        if (tid < OUTd) {
            float acc = rob[tid];
            const float* wp = roW + tid * 256;
            for (int s = 0; s < 256; s += 4) {
                f32x4 hv = *(const f32x4*)(fb + s);
                f32x4 w4 = *(const f32x4*)(wp + s);
                acc += hv[0] * w4[0] + hv[1] * w4[1] + hv[2] * w4[2] + hv[3] * w4[3];
            }
            out[((long)(b0c16 + sl) * 513 + Tt) * OUTd + tid] = acc;
        }
    }
}

extern "C" void kernel_launch(void* const* d_in, const int* in_sizes, int n_in,
                              void* d_out, int out_size, void* d_ws, size_t ws_size,
                              hipStream_t stream) {
    const float* x0      = (const float*)d_in[0];
    const float* logsigs = (const float*)d_in[1];
    const float* iW1 = (const float*)d_in[2];
    const float* ib1 = (const float*)d_in[3];
    const float* iW2 = (const float*)d_in[4];
    const float* ib2 = (const float*)d_in[5];
    const float* iW3 = (const float*)d_in[6];
    const float* ib3 = (const float*)d_in[7];
    const float* vW1 = (const float*)d_in[8];
    const float* vb1 = (const float*)d_in[9];
    const float* vW2 = (const float*)d_in[10];
    const float* vb2 = (const float*)d_in[11];
    const float* vW3 = (const float*)d_in[12];
    const float* vb3 = (const float*)d_in[13];
    const float* roW = (const float*)d_in[14];
    const float* rob = (const float*)d_in[15];
    float* out = (float*)d_out;

    char* p = (char*)d_ws;
    unsigned short* hA   = (unsigned short*)p;                // 131072 B (fp16)
    unsigned short* hB   = (unsigned short*)(p + 131072);     // 131072 B (fp16)
    unsigned short* w1t  = (unsigned short*)(p + 262144);     // 131072 B (fp16)
    unsigned short* w2t  = (unsigned short*)(p + 393216);     // 131072 B (fp16)
    unsigned short* w3t  = (unsigned short*)(p + 524288);     // 4718592 B (fp16)
    int* slots           = (int*)(p + 10485760);              // gbar [0,512], cbar [1024,1536]

    hipMemsetAsync(slots, 0, 8192, stream);
    rde_fused9<<<dim3(256), dim3(256), 0, stream>>>(
        x0, logsigs, iW1, ib1, iW2, ib2, iW3, ib3,
        vW1, vb1, vW2, vb2, vW3, vb3, roW, rob, out,
        hA, hB, w1t, w2t, w3t, slots);
}